// Round 1
// 226.286 us; speedup vs baseline: 1.0614x; 1.0614x over previous
//
#include <hip/hip_runtime.h>
#include <hip/hip_bf16.h>

typedef unsigned short u16;
typedef unsigned int u32;
typedef __attribute__((ext_vector_type(8))) short short8;   // 8 bf16 = 4 VGPRs
typedef __attribute__((ext_vector_type(4))) float f32x4;    // MFMA C/D frag

#define LRELU_SLOPE 0.2f
#define EPS_LN 1e-5f
#define EPS_SM 1e-16f
#define SCAN_CHUNK 4096   // 256 threads x 16 elems; chunk id = idx>>12

__device__ __forceinline__ float bflo(u32 u){ union{u32 i; float f;} x; x.i = u<<16; return x.f; }
__device__ __forceinline__ float bfhi(u32 u){ union{u32 i; float f;} x; x.i = u & 0xffff0000u; return x.f; }
__device__ __forceinline__ float bf1(u16 u){ union{u32 i; float f;} x; x.i = ((u32)u)<<16; return x.f; }
__device__ __forceinline__ u16 f2bf(float f){
  union{float f; u32 i;} x; x.f=f; u32 i=x.i;
  u32 r = (i + 0x7fffu + ((i>>16)&1u))>>16; return (u16)r;
}
__device__ __forceinline__ u32 pack2(float a, float b){ return (u32)f2bf(a) | ((u32)f2bf(b)<<16); }
__device__ __forceinline__ float lrelu(float x){ return x > 0.f ? x : LRELU_SLOPE*x; }

__device__ __forceinline__ float wsum(float v){
  #pragma unroll
  for(int o=32;o>0;o>>=1) v += __shfl_xor(v,o,64);
  return v;
}

// ---------------- LN1: xt = LayerNorm(x) (bf16 out) + deg zeroing ----------------
__global__ __launch_bounds__(256) void ln1_kernel(const float* __restrict__ x,
    const float* __restrict__ g, const float* __restrict__ b,
    u16* __restrict__ xt, int* __restrict__ deg, int n){
  if(threadIdx.x < 4){ int z = blockIdx.x*4 + threadIdx.x; if(z<n) deg[z]=0; }
  int row  = blockIdx.x*4 + (threadIdx.x>>6);
  int lane = threadIdx.x & 63;
  if(row >= n) return;
  float2 xv = ((const float2*)(x + (size_t)row*128))[lane];
  float v0 = xv.x, v1 = xv.y;
  float mean = wsum(v0+v1) * (1.f/128.f);
  float d0 = v0-mean, d1 = v1-mean;
  float var = wsum(d0*d0 + d1*d1) * (1.f/128.f);
  float rstd = rsqrtf(var + EPS_LN);
  float2 gv = ((const float2*)g)[lane], bv = ((const float2*)b)[lane];
  float o0 = d0*rstd*gv.x + bv.x;
  float o1 = d1*rstd*gv.y + bv.y;
  ((u32*)(xt + (size_t)row*128))[lane] = pack2(o0, o1);
}

// ---------------- MFMA GEMM: h = xt @ W (bf16) + logits + fused edge histogram ----
__global__ __launch_bounds__(256) void gemm_kernel(const u16* __restrict__ xt,
    const float* __restrict__ W, const float* __restrict__ att_src, const float* __restrict__ att_dst,
    u16* __restrict__ h, float* __restrict__ a_src, float* __restrict__ a_dst,
    const int* __restrict__ edst, int* __restrict__ deg, int E, int n){
  __shared__ u16 Wf[16384];      // 32 KB frag-major W
  __shared__ u16 Xb[64*136];     // 17 KB bf16 xt tile (pad 8 u16/row); reused for h staging
  int tid = threadIdx.x;
  int r0  = blockIdx.x*64;

  // fused histogram (deg zeroed by ln1 in previous dispatch)
  for(int e = blockIdx.x*256 + tid; e < E; e += gridDim.x*256)
    atomicAdd(&deg[edst[e]], 1);

  // stage W -> Wf: element W[k][n] at idx ((tile*4+ks)*64 + q*16 + c)*8 + j
  const float4* W4 = (const float4*)W;
  for(int p=tid; p<2048; p+=256){
    int g = p & 31, kk = p >> 5;
    int k0 = kk*2, n0 = g*4;
    float4 w0 = W4[k0*32 + g];
    float4 w1 = W4[(k0+1)*32 + g];
    int ks = k0>>5, q = (k0>>3)&3, j = k0&7;   // j even
    float e0[4] = {w0.x,w0.y,w0.z,w0.w};
    float e1[4] = {w1.x,w1.y,w1.z,w1.w};
    #pragma unroll
    for(int u=0;u<4;u++){
      int nn = n0+u;
      int idx = (((nn>>4)*4 + ks)*64 + q*16 + (nn&15))*8 + j;
      ((u32*)Wf)[idx>>1] = pack2(e0[u], e1[u]);
    }
  }
  // stage bf16 xt tile -> Xb (straight 16B copies)
  for(int i=tid; i<1024; i+=256){
    int row = i>>4, seg = i&15;
    int gr = r0+row;
    uint4 v = (gr<n) ? ((const uint4*)(xt + (size_t)gr*128))[seg] : make_uint4(0,0,0,0);
    *(uint4*)&Xb[row*136 + seg*8] = v;
  }
  __syncthreads();

  int w = tid>>6, lane = tid&63;
  int slab = w*16, c = lane&15, q = lane>>4;
  f32x4 acc[8];
  #pragma unroll
  for(int t=0;t<8;t++) acc[t] = (f32x4){0.f,0.f,0.f,0.f};
  #pragma unroll
  for(int ks=0;ks<4;ks++){
    short8 A = *(const short8*)&Xb[(slab + c)*136 + ks*32 + q*8];
    #pragma unroll
    for(int t=0;t<8;t++){
      short8 B = *(const short8*)&Wf[((t*4+ks)*64 + lane)*8];
      acc[t] = __builtin_amdgcn_mfma_f32_16x16x32_bf16(A, B, acc[t], 0, 0, 0);
    }
  }
  __syncthreads();   // all waves done reading Xb
  // D-frags -> Xb as bf16 h tile. C/D layout: col=lane&15, row=q*4+reg.
  #pragma unroll
  for(int t=0;t<8;t++){
    #pragma unroll
    for(int r=0;r<4;r++){
      Xb[(slab + q*4 + r)*136 + t*16 + c] = f2bf(acc[t][r]);
    }
  }
  __syncthreads();
  // coalesced h write + logits; thread p -> row p>>2, quarter qt (64B = 4x uint4)
  {
    int row = tid>>2, qt = tid&3;
    int gr = r0+row;
    if(gr<n){
      const uint4* src = (const uint4*)((const char*)Xb + row*272 + qt*64);
      uint4* dst = (uint4*)((char*)(h + (size_t)gr*128) + qt*64);
      dst[0] = src[0];
      dst[1] = src[1];
      dst[2] = src[2];
      dst[3] = src[3];
    }
    int hd = qt;
    if(gr<n){
      float as=0.f, ad=0.f;
      const u16* hp = &Xb[row*136 + hd*32];
      #pragma unroll
      for(int sgm=0;sgm<4;sgm++){
        #pragma unroll
        for(int e=0;e<8;e++){
          float v = bf1(hp[sgm*8+e]);
          as = fmaf(v, att_src[hd*32+sgm*8+e], as);
          ad = fmaf(v, att_dst[hd*32+sgm*8+e], ad);
        }
      }
      a_src[(size_t)gr*4+hd] = as;
      a_dst[(size_t)gr*4+hd] = ad;
    }
  }
}

// ---------------- CSR build (2-level: chunk-local prefixes + bsum offsets) --------
// scanA: rowptr[idx] (idx<=n) and cursor[idx] (idx<n) get CHUNK-LOCAL prefixes.
__global__ __launch_bounds__(256) void scanA_kernel(const int* __restrict__ deg,
    int* __restrict__ rowptr, int* __restrict__ cursor, int* __restrict__ bsum, int n){
  __shared__ int part[256];
  int tid = threadIdx.x;
  int base = blockIdx.x*SCAN_CHUNK + tid*16;
  int v[16]; int s=0;
  #pragma unroll
  for(int i=0;i<16;i++){ int idx=base+i; int xv=(idx<n)? deg[idx]:0; v[i]=s; s+=xv; }
  part[tid]=s; __syncthreads();
  int mys=s;
  for(int off=1;off<256;off<<=1){
    int t = (tid>=off)? part[tid-off] : 0;
    __syncthreads(); part[tid]+=t; __syncthreads();
  }
  int run = part[tid]-mys;
  #pragma unroll
  for(int i=0;i<16;i++){
    int idx=base+i;
    if(idx<=n) rowptr[idx]=v[i]+run;
    if(idx<n)  cursor[idx]=v[i]+run;
  }
  if(tid==255) bsum[blockIdx.x]=part[255];
}
// scanB: in-place exclusive scan of chunk totals (nb <= 64).
__global__ __launch_bounds__(64) void scanB_kernel(int* __restrict__ bsum, int nb){
  int lane = threadIdx.x;
  int v = (lane<nb)? bsum[lane] : 0;
  int inc = v;
  #pragma unroll
  for(int o=1;o<64;o<<=1){ int t=__shfl_up(inc,o,64); if(lane>=o) inc+=t; }
  if(lane<nb) bsum[lane] = inc - v;
}
__global__ void scatter_kernel(const int* __restrict__ src, const int* __restrict__ dst,
    int* __restrict__ cursor, const int* __restrict__ bsum, int* __restrict__ col, int E){
  int e = blockIdx.x*blockDim.x + threadIdx.x;
  if(e<E){
    int d=dst[e];
    int pos = bsum[d>>12] + atomicAdd(&cursor[d],1);
    col[pos]=src[e];
  }
}

// ---------------- Aggregation: softmax (no max pass) + gather + residual + LN2 ----
// RESTRUCTURED: 16-lane group per dst, 4 dsts per wave (avg degree = E/N = 12, so a
// 64-lane wave per dst wasted ~80% of y-pass lanes and paid 64-wide reductions per
// dst). Group layout: li = lane&15 owns channels li*8..li*8+7 (head hc = li>>2);
// the 16 lanes' uint4 loads exactly cover one 256B bf16 h row. Per gather
// iteration the wave still processes 4 edges (one per group) = 1KB of h, same
// rate as before, but the y-pass, softmax reductions, self-loop, and LN2 are all
// amortized 4x, and the cross-quarter acc reduction disappears (each lane owns
// its channels exclusively). expf -> __expf (native v_exp) throughout.
// Softmax shift-invariance: no max subtraction (logits ~<10, clamp 60 for safety).
__global__ __launch_bounds__(256) void agg_kernel(const u16* __restrict__ h,
    const float* __restrict__ a_src, const float* __restrict__ a_dst,
    const int* __restrict__ rowptr, const int* __restrict__ bsum, const int* __restrict__ col,
    const u16* __restrict__ xt, const float* __restrict__ bias,
    const float* __restrict__ g2, const float* __restrict__ b2,
    float* __restrict__ out, int n){
  int lane = threadIdx.x & 63;
  int wv   = threadIdx.x >> 6;
  int g    = lane >> 4;        // group within wave
  int li   = lane & 15;        // lane within group
  int hc   = li >> 2;          // head of this lane's 8 channels
  int d    = blockIdx.x*16 + wv*4 + g;
  bool dok = d < n;
  int dc   = dok ? d : (n-1);  // clamped index: keep all lanes alive for shfls

  float4 ad  = ((const float4*)a_dst)[dc];
  float4 asd = ((const float4*)a_src)[dc];
  float ad_h = hc==0? ad.x  : hc==1? ad.y  : hc==2? ad.z  : ad.w;
  float as_h = hc==0? asd.x : hc==1? asd.y : hc==2? asd.z : asd.w;
  float t_h  = __expf(fminf(lrelu(as_h + ad_h), 60.f));   // self-loop term, own head

  int base = rowptr[dc] + bsum[dc>>12];
  int d1   = dc+1;
  int end  = rowptr[d1] + bsum[d1>>12];
  int deg  = dok ? (end - base) : 0;
  // wave-uniform max degree over the 4 groups (deg identical within a group)
  int dm = deg;
  dm = max(dm, __shfl_xor(dm, 16, 64));
  dm = max(dm, __shfl_xor(dm, 32, 64));

  float p0=0.f,p1=0.f,p2=0.f,p3=0.f;
  float acc[8]={};
  for(int j0=0;j0<dm;j0+=16){
    int j = j0 + li;
    bool vv = j < deg;
    int sx = vv ? col[base+j] : 0;       // sx=0 for padding: al will be 0
    float4 a = ((const float4*)a_src)[sx];
    float y0 = vv ? __expf(fminf(lrelu(a.x+ad.x),60.f)) : 0.f;
    float y1 = vv ? __expf(fminf(lrelu(a.y+ad.y),60.f)) : 0.f;
    float y2 = vv ? __expf(fminf(lrelu(a.z+ad.z),60.f)) : 0.f;
    float y3 = vv ? __expf(fminf(lrelu(a.w+ad.w),60.f)) : 0.f;
    p0+=y0; p1+=y1; p2+=y2; p3+=y3;
    int ccm = min(dm - j0, 16);          // wave-uniform trip count
    int gbase = g<<4;
    for(int jj=0; jj<ccm; jj++){
      int srcl = gbase + jj;
      float f0=__shfl(y0,srcl,64), f1=__shfl(y1,srcl,64);
      float f2=__shfl(y2,srcl,64), f3=__shfl(y3,srcl,64);
      int   sj=__shfl(sx,srcl,64);
      float al = hc==0? f0 : hc==1? f1 : hc==2? f2 : f3;
      uint4 hv = *(const uint4*)(h + (size_t)sj*128 + li*8);
      acc[0]=fmaf(al,bflo(hv.x),acc[0]); acc[1]=fmaf(al,bfhi(hv.x),acc[1]);
      acc[2]=fmaf(al,bflo(hv.y),acc[2]); acc[3]=fmaf(al,bfhi(hv.y),acc[3]);
      acc[4]=fmaf(al,bflo(hv.z),acc[4]); acc[5]=fmaf(al,bfhi(hv.z),acc[5]);
      acc[6]=fmaf(al,bflo(hv.w),acc[6]); acc[7]=fmaf(al,bfhi(hv.w),acc[7]);
    }
  }
  // 16-lane group reduction of the per-head exp sums (serves 4 dsts per step)
  #pragma unroll
  for(int o=1;o<16;o<<=1){
    p0+=__shfl_xor(p0,o,64); p1+=__shfl_xor(p1,o,64);
    p2+=__shfl_xor(p2,o,64); p3+=__shfl_xor(p3,o,64);
  }
  float den = (hc==0? p0 : hc==1? p1 : hc==2? p2 : p3) + t_h + EPS_SM;
  // self-loop message (each lane owns its channels; no cross-lane acc reduce)
  uint4 hd4 = *(const uint4*)(h + (size_t)dc*128 + li*8);
  acc[0]=fmaf(t_h,bflo(hd4.x),acc[0]); acc[1]=fmaf(t_h,bfhi(hd4.x),acc[1]);
  acc[2]=fmaf(t_h,bflo(hd4.y),acc[2]); acc[3]=fmaf(t_h,bfhi(hd4.y),acc[3]);
  acc[4]=fmaf(t_h,bflo(hd4.z),acc[4]); acc[5]=fmaf(t_h,bfhi(hd4.z),acc[5]);
  acc[6]=fmaf(t_h,bflo(hd4.w),acc[6]); acc[7]=fmaf(t_h,bfhi(hd4.w),acc[7]);
  float inv = 1.f/den;

  // bias + residual (bf16 xt) + LN2 (each channel counted once over 16 lanes -> /128)
  uint4 xv4 = *(const uint4*)(xt + (size_t)dc*128 + li*8);
  const float* bp = bias + li*8;
  float4 ba = *(const float4*)bp, bb = *(const float4*)(bp+4);
  float r[8];
  r[0]=bflo(xv4.x)+acc[0]*inv+ba.x; r[1]=bfhi(xv4.x)+acc[1]*inv+ba.y;
  r[2]=bflo(xv4.y)+acc[2]*inv+ba.z; r[3]=bfhi(xv4.y)+acc[3]*inv+ba.w;
  r[4]=bflo(xv4.z)+acc[4]*inv+bb.x; r[5]=bfhi(xv4.z)+acc[5]*inv+bb.y;
  r[6]=bflo(xv4.w)+acc[6]*inv+bb.z; r[7]=bfhi(xv4.w)+acc[7]*inv+bb.w;
  float part=0;
  #pragma unroll
  for(int c=0;c<8;c++) part+=r[c];
  #pragma unroll
  for(int o=1;o<16;o<<=1) part += __shfl_xor(part,o,64);
  float mean = part*(1.f/128.f);
  float vp=0;
  #pragma unroll
  for(int c=0;c<8;c++){ float dd=r[c]-mean; vp+=dd*dd; }
  #pragma unroll
  for(int o=1;o<16;o<<=1) vp += __shfl_xor(vp,o,64);
  float var = vp*(1.f/128.f);
  float rstd = rsqrtf(var+EPS_LN);
  const float* gp = g2 + li*8; const float* b2p = b2 + li*8;
  float4 ga = *(const float4*)gp,  gb = *(const float4*)(gp+4);
  float4 c2a= *(const float4*)b2p, c2b= *(const float4*)(b2p+4);
  if(dok){
    float* op = out + (size_t)d*128 + li*8;
    float4 o0 = make_float4((r[0]-mean)*rstd*ga.x+c2a.x, (r[1]-mean)*rstd*ga.y+c2a.y,
                            (r[2]-mean)*rstd*ga.z+c2a.z, (r[3]-mean)*rstd*ga.w+c2a.w);
    float4 o1 = make_float4((r[4]-mean)*rstd*gb.x+c2b.x, (r[5]-mean)*rstd*gb.y+c2b.y,
                            (r[6]-mean)*rstd*gb.z+c2b.z, (r[7]-mean)*rstd*gb.w+c2b.w);
    *(float4*)op     = o0;
    *(float4*)(op+4) = o1;
  }
}

extern "C" void kernel_launch(void* const* d_in, const int* in_sizes, int n_in,
                              void* d_out, int out_size, void* d_ws, size_t ws_size,
                              hipStream_t stream) {
  const float* x     = (const float*)d_in[0];
  const int*   ei    = (const int*)d_in[1];
  const float* W     = (const float*)d_in[4];
  const float* att_s = (const float*)d_in[5];
  const float* att_d = (const float*)d_in[6];
  const float* bias  = (const float*)d_in[7];
  const float* g1    = (const float*)d_in[8];
  const float* b1    = (const float*)d_in[9];
  const float* g2    = (const float*)d_in[10];
  const float* b2    = (const float*)d_in[11];
  int n = in_sizes[0]/128;
  int E = in_sizes[1]/2;
  float* out = (float*)d_out;

  char* ws = (char*)d_ws;
  u16*   xt    = (u16*)ws;   ws += (size_t)n*128*2;
  u16*   h     = (u16*)ws;   ws += (size_t)n*128*2;
  float* a_src = (float*)ws; ws += (size_t)n*4*4;
  float* a_dst = (float*)ws; ws += (size_t)n*4*4;
  int* deg     = (int*)ws;   ws += (size_t)n*4;
  int* rowptr  = (int*)ws;   ws += (((size_t)(n+1)*4 + 255) & ~(size_t)255);
  int* cursor  = (int*)ws;   ws += (size_t)n*4;
  int* bsum    = (int*)ws;   ws += 256;
  int* col     = (int*)ws;   ws += (size_t)E*4;

  int nb = n/SCAN_CHUNK + 1;   // guarantees idx=n falls inside chunk nb-1

  dim3 b256(256);
  ln1_kernel    <<<(n+3)/4,     b256, 0, stream>>>(x, g1, b1, xt, deg, n);
  gemm_kernel   <<<(n+63)/64,   b256, 0, stream>>>(xt, W, att_s, att_d, h, a_src, a_dst, ei+E, deg, E, n);
  scanA_kernel  <<<nb,          b256, 0, stream>>>(deg, rowptr, cursor, bsum, n);
  scanB_kernel  <<<1,           64,   0, stream>>>(bsum, nb);
  scatter_kernel<<<(E+255)/256, b256, 0, stream>>>(ei, ei+E, cursor, bsum, col, E);
  agg_kernel    <<<(n+15)/16,   b256, 0, stream>>>(h, a_src, a_dst, rowptr, bsum, col, xt, bias, g2, b2, out, n);
}

// Round 3
// 191.445 us; speedup vs baseline: 1.2546x; 1.1820x over previous
//
#include <hip/hip_runtime.h>
#include <hip/hip_bf16.h>

typedef unsigned short u16;
typedef unsigned int u32;
typedef __attribute__((ext_vector_type(8))) short short8;   // 8 bf16 = 4 VGPRs
typedef __attribute__((ext_vector_type(4))) float f32x4;    // MFMA C/D frag

#define LRELU_SLOPE 0.2f
#define EPS_LN 1e-5f
#define EPS_SM 1e-16f
#define SCAN_CHUNK 4096   // 256 threads x 16 elems; chunk id = idx>>12
#define NBLK 256          // edge-chunk blocks for binA/binC
// Bucketed CSR build: bucket = dst>>7 (128 dsts/bucket). Requires n <= 65536
// (src packs in 16 bits) and NB <= 512 (LDS arrays). n = 50000 -> NB = 391.
// CSR scratch (ebuf/bhT/bhpref/bsum2) overlays the h buffer: h is written by
// gemm_kernel which launches AFTER binD, so lifetimes are disjoint.

__device__ __forceinline__ float bflo(u32 u){ union{u32 i; float f;} x; x.i = u<<16; return x.f; }
__device__ __forceinline__ float bfhi(u32 u){ union{u32 i; float f;} x; x.i = u & 0xffff0000u; return x.f; }
__device__ __forceinline__ float bf1(u16 u){ union{u32 i; float f;} x; x.i = ((u32)u)<<16; return x.f; }
__device__ __forceinline__ u16 f2bf(float f){
  union{float f; u32 i;} x; x.f=f; u32 i=x.i;
  u32 r = (i + 0x7fffu + ((i>>16)&1u))>>16; return (u16)r;
}
__device__ __forceinline__ u32 pack2(float a, float b){ return (u32)f2bf(a) | ((u32)f2bf(b)<<16); }
__device__ __forceinline__ float lrelu(float x){ return x > 0.f ? x : LRELU_SLOPE*x; }

__device__ __forceinline__ float wsum(float v){
  #pragma unroll
  for(int o=32;o>0;o>>=1) v += __shfl_xor(v,o,64);
  return v;
}

// ---------------- LN1: xt = LayerNorm(x) (bf16 out) ----------------
__global__ __launch_bounds__(256) void ln1_kernel(const float* __restrict__ x,
    const float* __restrict__ g, const float* __restrict__ b,
    u16* __restrict__ xt, int n){
  int row  = blockIdx.x*4 + (threadIdx.x>>6);
  int lane = threadIdx.x & 63;
  if(row >= n) return;
  float2 xv = ((const float2*)(x + (size_t)row*128))[lane];
  float v0 = xv.x, v1 = xv.y;
  float mean = wsum(v0+v1) * (1.f/128.f);
  float d0 = v0-mean, d1 = v1-mean;
  float var = wsum(d0*d0 + d1*d1) * (1.f/128.f);
  float rstd = rsqrtf(var + EPS_LN);
  float2 gv = ((const float2*)g)[lane], bv = ((const float2*)b)[lane];
  float o0 = d0*rstd*gv.x + bv.x;
  float o1 = d1*rstd*gv.y + bv.y;
  ((u32*)(xt + (size_t)row*128))[lane] = pack2(o0, o1);
}

// ---------------- MFMA GEMM: h = xt @ W (bf16) + attention logits ----------------
__global__ __launch_bounds__(256) void gemm_kernel(const u16* __restrict__ xt,
    const float* __restrict__ W, const float* __restrict__ att_src, const float* __restrict__ att_dst,
    u16* __restrict__ h, float* __restrict__ a_src, float* __restrict__ a_dst, int n){
  __shared__ u16 Wf[16384];      // 32 KB frag-major W
  __shared__ u16 Xb[64*136];     // 17 KB bf16 xt tile (pad 8 u16/row); reused for h staging
  int tid = threadIdx.x;
  int r0  = blockIdx.x*64;

  // stage W -> Wf: element W[k][n] at idx ((tile*4+ks)*64 + q*16 + c)*8 + j
  const float4* W4 = (const float4*)W;
  for(int p=tid; p<2048; p+=256){
    int g = p & 31, kk = p >> 5;
    int k0 = kk*2, n0 = g*4;
    float4 w0 = W4[k0*32 + g];
    float4 w1 = W4[(k0+1)*32 + g];
    int ks = k0>>5, q = (k0>>3)&3, j = k0&7;   // j even
    float e0[4] = {w0.x,w0.y,w0.z,w0.w};
    float e1[4] = {w1.x,w1.y,w1.z,w1.w};
    #pragma unroll
    for(int u=0;u<4;u++){
      int nn = n0+u;
      int idx = (((nn>>4)*4 + ks)*64 + q*16 + (nn&15))*8 + j;
      ((u32*)Wf)[idx>>1] = pack2(e0[u], e1[u]);
    }
  }
  // stage bf16 xt tile -> Xb (straight 16B copies)
  for(int i=tid; i<1024; i+=256){
    int row = i>>4, seg = i&15;
    int gr = r0+row;
    uint4 v = (gr<n) ? ((const uint4*)(xt + (size_t)gr*128))[seg] : make_uint4(0,0,0,0);
    *(uint4*)&Xb[row*136 + seg*8] = v;
  }
  __syncthreads();

  int w = tid>>6, lane = tid&63;
  int slab = w*16, c = lane&15, q = lane>>4;
  f32x4 acc[8];
  #pragma unroll
  for(int t=0;t<8;t++) acc[t] = (f32x4){0.f,0.f,0.f,0.f};
  #pragma unroll
  for(int ks=0;ks<4;ks++){
    short8 A = *(const short8*)&Xb[(slab + c)*136 + ks*32 + q*8];
    #pragma unroll
    for(int t=0;t<8;t++){
      short8 B = *(const short8*)&Wf[((t*4+ks)*64 + lane)*8];
      acc[t] = __builtin_amdgcn_mfma_f32_16x16x32_bf16(A, B, acc[t], 0, 0, 0);
    }
  }
  __syncthreads();   // all waves done reading Xb
  // D-frags -> Xb as bf16 h tile. C/D layout: col=lane&15, row=q*4+reg.
  #pragma unroll
  for(int t=0;t<8;t++){
    #pragma unroll
    for(int r=0;r<4;r++){
      Xb[(slab + q*4 + r)*136 + t*16 + c] = f2bf(acc[t][r]);
    }
  }
  __syncthreads();
  // coalesced h write + logits; thread p -> row p>>2, quarter qt (64B = 4x uint4)
  {
    int row = tid>>2, qt = tid&3;
    int gr = r0+row;
    if(gr<n){
      const uint4* src = (const uint4*)((const char*)Xb + row*272 + qt*64);
      uint4* dst = (uint4*)((char*)(h + (size_t)gr*128) + qt*64);
      dst[0] = src[0];
      dst[1] = src[1];
      dst[2] = src[2];
      dst[3] = src[3];
    }
    int hd = qt;
    if(gr<n){
      float as=0.f, ad=0.f;
      const u16* hp = &Xb[row*136 + hd*32];
      #pragma unroll
      for(int sgm=0;sgm<4;sgm++){
        #pragma unroll
        for(int e=0;e<8;e++){
          float v = bf1(hp[sgm*8+e]);
          as = fmaf(v, att_src[hd*32+sgm*8+e], as);
          ad = fmaf(v, att_dst[hd*32+sgm*8+e], ad);
        }
      }
      a_src[(size_t)gr*4+hd] = as;
      a_dst[(size_t)gr*4+hd] = ad;
    }
  }
}

// ---------------- Bucketed CSR build (replaces global-atomic histogram+scatter) ----
// binA: per-block LDS histogram over NB coarse buckets; store transposed counts
// bhT[b*NBLK + i] (bucket-major) so a linear scan gives per-(bucket,block) offsets.
__global__ __launch_bounds__(256) void binA_kernel(const int* __restrict__ dst,
    int* __restrict__ bhT, int E, int CH, int NB){
  __shared__ u32 hist[512];
  int tid = threadIdx.x, i = blockIdx.x;
  for(int b=tid; b<NB; b+=256) hist[b]=0;
  __syncthreads();
  int e0=i*CH, e1=min(E, e0+CH);
  for(int e=e0+tid; e<e1; e+=256) atomicAdd(&hist[(u32)dst[e]>>7], 1u);
  __syncthreads();
  for(int b=tid; b<NB; b+=256) bhT[b*NBLK + i] = (int)hist[b];
}

// scanA: chunk-local exclusive prefixes of an int array (pref[idx], idx<=n) + chunk sums.
__global__ __launch_bounds__(256) void scanA_kernel(const int* __restrict__ deg,
    int* __restrict__ pref, int* __restrict__ bsum, int n){
  __shared__ int part[256];
  int tid = threadIdx.x;
  int base = blockIdx.x*SCAN_CHUNK + tid*16;
  int v[16]; int s=0;
  #pragma unroll
  for(int i=0;i<16;i++){ int idx=base+i; int xv=(idx<n)? deg[idx]:0; v[i]=s; s+=xv; }
  part[tid]=s; __syncthreads();
  int mys=s;
  for(int off=1;off<256;off<<=1){
    int t = (tid>=off)? part[tid-off] : 0;
    __syncthreads(); part[tid]+=t; __syncthreads();
  }
  int run = part[tid]-mys;
  #pragma unroll
  for(int i=0;i<16;i++){
    int idx=base+i;
    if(idx<=n) pref[idx]=v[i]+run;
  }
  if(tid==255) bsum[blockIdx.x]=part[255];
}
// scanB: in-place exclusive scan of chunk totals (nb <= 64).
__global__ __launch_bounds__(64) void scanB_kernel(int* __restrict__ bsum, int nb){
  int lane = threadIdx.x;
  int v = (lane<nb)? bsum[lane] : 0;
  int inc = v;
  #pragma unroll
  for(int o=1;o<64;o<<=1){ int t=__shfl_up(inc,o,64); if(lane>=o) inc+=t; }
  if(lane<nb) bsum[lane] = inc - v;
}

// binC: re-read edge chunk; place each edge in its bucket region at
// prefix(bucket,block) + LDS-cursor++. Store src | (local_dst << 16), 4B each.
__global__ __launch_bounds__(256) void binC_kernel(const int* __restrict__ src,
    const int* __restrict__ dst, const int* __restrict__ bhpref, const int* __restrict__ bsum2,
    u32* __restrict__ ebuf, int E, int CH, int NB){
  __shared__ u32 cur[512];
  int tid = threadIdx.x, i = blockIdx.x;
  for(int b=tid; b<NB; b+=256){
    int j = b*NBLK + i;
    cur[b] = (u32)(bhpref[j] + bsum2[j>>12]);
  }
  __syncthreads();
  int e0=i*CH, e1=min(E, e0+CH);
  for(int e=e0+tid; e<e1; e+=256){
    u32 s = (u32)src[e], d = (u32)dst[e];
    u32 pos = atomicAdd(&cur[d>>7], 1u);
    ebuf[pos] = s | ((d & 127u) << 16);
  }
}

// binD: one block per bucket. LDS count over 128 local dsts -> LDS scan ->
// absolute rowptr + in-bucket scatter into col (u16 src ids). All atomics on-chip.
__global__ __launch_bounds__(256) void binD_kernel(const u32* __restrict__ ebuf,
    const int* __restrict__ bhpref, const int* __restrict__ bsum2,
    int* __restrict__ rowptr, u16* __restrict__ col, int n, int E){
  __shared__ int cnt[128], cur[128];
  int tid = threadIdx.x, b = blockIdx.x;
  int j0 = b*NBLK, j1 = (b+1)*NBLK;
  int base = bhpref[j0] + bsum2[j0>>12];
  int end  = bhpref[j1] + bsum2[j1>>12];   // j1 <= NB*NBLK, pref[NH] = E
  int cb = end - base;
  if(tid<128) cnt[tid]=0;
  __syncthreads();
  for(int k=tid; k<cb; k+=256) atomicAdd(&cnt[(ebuf[base+k]>>16)&127], 1);
  __syncthreads();
  // inclusive scan of cnt (Hillis-Steele ladder)
  for(int o=1;o<128;o<<=1){
    int t = (tid>=o && tid<128)? cnt[tid-o] : 0;
    __syncthreads();
    if(tid<128) cnt[tid]+=t;
    __syncthreads();
  }
  int nd = min(128, n - (b<<7));
  if(tid<128){
    int excl = tid? cnt[tid-1] : 0;
    cur[tid] = excl;
    if(tid<nd) rowptr[(b<<7)+tid] = base + excl;
  }
  if(b==0 && tid==0) rowptr[n] = E;
  __syncthreads();
  for(int k=tid; k<cb; k+=256){
    u32 v = ebuf[base+k];
    int l = (int)((v>>16)&127u);
    int p = atomicAdd(&cur[l], 1);
    col[base+p] = (u16)(v & 0xffffu);
  }
}

// ---------------- Aggregation: softmax (no max pass) + gather + residual + LN2 ----
// 16-lane group per dst, 4 dsts per wave. li = lane&15 owns channels li*8..li*8+7
// (head hc = li>>2); 16 lanes' uint4 loads cover one 256B bf16 h row. Absolute
// rowptr. Softmax shift-invariance: no max subtraction (logits ~<10, clamp 60).
__global__ __launch_bounds__(256) void agg_kernel(const u16* __restrict__ h,
    const float* __restrict__ a_src, const float* __restrict__ a_dst,
    const int* __restrict__ rowptr, const u16* __restrict__ col,
    const u16* __restrict__ xt, const float* __restrict__ bias,
    const float* __restrict__ g2, const float* __restrict__ b2,
    float* __restrict__ out, int n){
  int lane = threadIdx.x & 63;
  int wv   = threadIdx.x >> 6;
  int g    = lane >> 4;        // group within wave
  int li   = lane & 15;        // lane within group
  int hc   = li >> 2;          // head of this lane's 8 channels
  int d    = blockIdx.x*16 + wv*4 + g;
  bool dok = d < n;
  int dc   = dok ? d : (n-1);  // clamped index: keep all lanes alive for shfls

  float4 ad  = ((const float4*)a_dst)[dc];
  float4 asd = ((const float4*)a_src)[dc];
  float ad_h = hc==0? ad.x  : hc==1? ad.y  : hc==2? ad.z  : ad.w;
  float as_h = hc==0? asd.x : hc==1? asd.y : hc==2? asd.z : asd.w;
  float t_h  = __expf(fminf(lrelu(as_h + ad_h), 60.f));   // self-loop term, own head

  int base = rowptr[dc];
  int end  = rowptr[dc+1];
  int deg  = dok ? (end - base) : 0;
  // wave-uniform max degree over the 4 groups (deg identical within a group)
  int dm = deg;
  dm = max(dm, __shfl_xor(dm, 16, 64));
  dm = max(dm, __shfl_xor(dm, 32, 64));

  float p0=0.f,p1=0.f,p2=0.f,p3=0.f;
  float acc[8]={};
  for(int j0=0;j0<dm;j0+=16){
    int j = j0 + li;
    bool vv = j < deg;
    int sx = vv ? (int)col[base+j] : 0;  // sx=0 for padding: al will be 0
    float4 a = ((const float4*)a_src)[sx];
    float y0 = vv ? __expf(fminf(lrelu(a.x+ad.x),60.f)) : 0.f;
    float y1 = vv ? __expf(fminf(lrelu(a.y+ad.y),60.f)) : 0.f;
    float y2 = vv ? __expf(fminf(lrelu(a.z+ad.z),60.f)) : 0.f;
    float y3 = vv ? __expf(fminf(lrelu(a.w+ad.w),60.f)) : 0.f;
    p0+=y0; p1+=y1; p2+=y2; p3+=y3;
    int ccm = min(dm - j0, 16);          // wave-uniform trip count
    int gbase = g<<4;
    for(int jj=0; jj<ccm; jj++){
      int srcl = gbase + jj;
      float f0=__shfl(y0,srcl,64), f1=__shfl(y1,srcl,64);
      float f2=__shfl(y2,srcl,64), f3=__shfl(y3,srcl,64);
      int   sj=__shfl(sx,srcl,64);
      float al = hc==0? f0 : hc==1? f1 : hc==2? f2 : f3;
      uint4 hv = *(const uint4*)(h + (size_t)sj*128 + li*8);
      acc[0]=fmaf(al,bflo(hv.x),acc[0]); acc[1]=fmaf(al,bfhi(hv.x),acc[1]);
      acc[2]=fmaf(al,bflo(hv.y),acc[2]); acc[3]=fmaf(al,bfhi(hv.y),acc[3]);
      acc[4]=fmaf(al,bflo(hv.z),acc[4]); acc[5]=fmaf(al,bfhi(hv.z),acc[5]);
      acc[6]=fmaf(al,bflo(hv.w),acc[6]); acc[7]=fmaf(al,bfhi(hv.w),acc[7]);
    }
  }
  // 16-lane group reduction of the per-head exp sums (serves 4 dsts per step)
  #pragma unroll
  for(int o=1;o<16;o<<=1){
    p0+=__shfl_xor(p0,o,64); p1+=__shfl_xor(p1,o,64);
    p2+=__shfl_xor(p2,o,64); p3+=__shfl_xor(p3,o,64);
  }
  float den = (hc==0? p0 : hc==1? p1 : hc==2? p2 : p3) + t_h + EPS_SM;
  // self-loop message (each lane owns its channels; no cross-lane acc reduce)
  uint4 hd4 = *(const uint4*)(h + (size_t)dc*128 + li*8);
  acc[0]=fmaf(t_h,bflo(hd4.x),acc[0]); acc[1]=fmaf(t_h,bfhi(hd4.x),acc[1]);
  acc[2]=fmaf(t_h,bflo(hd4.y),acc[2]); acc[3]=fmaf(t_h,bfhi(hd4.y),acc[3]);
  acc[4]=fmaf(t_h,bflo(hd4.z),acc[4]); acc[5]=fmaf(t_h,bfhi(hd4.z),acc[5]);
  acc[6]=fmaf(t_h,bflo(hd4.w),acc[6]); acc[7]=fmaf(t_h,bfhi(hd4.w),acc[7]);
  float inv = 1.f/den;

  // bias + residual (bf16 xt) + LN2 (each channel counted once over 16 lanes -> /128)
  uint4 xv4 = *(const uint4*)(xt + (size_t)dc*128 + li*8);
  const float* bp = bias + li*8;
  float4 ba = *(const float4*)bp, bb = *(const float4*)(bp+4);
  float r[8];
  r[0]=bflo(xv4.x)+acc[0]*inv+ba.x; r[1]=bfhi(xv4.x)+acc[1]*inv+ba.y;
  r[2]=bflo(xv4.y)+acc[2]*inv+ba.z; r[3]=bfhi(xv4.y)+acc[3]*inv+ba.w;
  r[4]=bflo(xv4.z)+acc[4]*inv+bb.x; r[5]=bfhi(xv4.z)+acc[5]*inv+bb.y;
  r[6]=bflo(xv4.w)+acc[6]*inv+bb.z; r[7]=bfhi(xv4.w)+acc[7]*inv+bb.w;
  float part=0;
  #pragma unroll
  for(int c=0;c<8;c++) part+=r[c];
  #pragma unroll
  for(int o=1;o<16;o<<=1) part += __shfl_xor(part,o,64);
  float mean = part*(1.f/128.f);
  float vp=0;
  #pragma unroll
  for(int c=0;c<8;c++){ float dd=r[c]-mean; vp+=dd*dd; }
  #pragma unroll
  for(int o=1;o<16;o<<=1) vp += __shfl_xor(vp,o,64);
  float var = vp*(1.f/128.f);
  float rstd = rsqrtf(var+EPS_LN);
  const float* gp = g2 + li*8; const float* b2p = b2 + li*8;
  float4 ga = *(const float4*)gp,  gb = *(const float4*)(gp+4);
  float4 c2a= *(const float4*)b2p, c2b= *(const float4*)(b2p+4);
  if(dok){
    float* op = out + (size_t)d*128 + li*8;
    float4 o0 = make_float4((r[0]-mean)*rstd*ga.x+c2a.x, (r[1]-mean)*rstd*ga.y+c2a.y,
                            (r[2]-mean)*rstd*ga.z+c2a.z, (r[3]-mean)*rstd*ga.w+c2a.w);
    float4 o1 = make_float4((r[4]-mean)*rstd*gb.x+c2b.x, (r[5]-mean)*rstd*gb.y+c2b.y,
                            (r[6]-mean)*rstd*gb.z+c2b.z, (r[7]-mean)*rstd*gb.w+c2b.w);
    *(float4*)op     = o0;
    *(float4*)(op+4) = o1;
  }
}

extern "C" void kernel_launch(void* const* d_in, const int* in_sizes, int n_in,
                              void* d_out, int out_size, void* d_ws, size_t ws_size,
                              hipStream_t stream) {
  const float* x     = (const float*)d_in[0];
  const int*   ei    = (const int*)d_in[1];
  const float* W     = (const float*)d_in[4];
  const float* att_s = (const float*)d_in[5];
  const float* att_d = (const float*)d_in[6];
  const float* bias  = (const float*)d_in[7];
  const float* g1    = (const float*)d_in[8];
  const float* b1    = (const float*)d_in[9];
  const float* g2    = (const float*)d_in[10];
  const float* b2    = (const float*)d_in[11];
  int n = in_sizes[0]/128;
  int E = in_sizes[1]/2;
  float* out = (float*)d_out;

  int NB = (n+127)>>7;                 // coarse buckets (391 for n=50000)
  int CH = (E + NBLK - 1)/NBLK;        // edges per binA/binC block
  int NH = NB*NBLK;                    // flattened (bucket,block) table size
  int nb2 = NH/SCAN_CHUNK + 1;         // scan chunks over the table (25)

  char* ws = (char*)d_ws;
  u16*   xt     = (u16*)ws;   ws += (size_t)n*128*2;
  u16*   h      = (u16*)ws;   ws += (size_t)n*128*2;
  float* a_src  = (float*)ws; ws += (size_t)n*4*4;
  float* a_dst  = (float*)ws; ws += (size_t)n*4*4;
  int*   rowptr = (int*)ws;   ws += (((size_t)(n+1)*4 + 255) & ~(size_t)255);
  u16*   col    = (u16*)ws;   ws += (((size_t)E*2 + 255) & ~(size_t)255);
  // CSR scratch overlays h (h is dead until gemm_kernel, launched after binD)
  char* hs = (char*)h;
  u32*   ebuf   = (u32*)hs;                 hs += (size_t)E*4;
  int*   bhT    = (int*)hs;                 hs += (size_t)NH*4;
  int*   bhpref = (int*)hs;                 hs += (((size_t)(NH+1)*4 + 255) & ~(size_t)255);
  int*   bsum2  = (int*)hs;                 // 256 ints; total overlay ~3.2MB << 12.8MB

  dim3 b256(256);
  ln1_kernel  <<<(n+3)/4,   b256, 0, stream>>>(x, g1, b1, xt, n);
  binA_kernel <<<NBLK,      b256, 0, stream>>>(ei+E, bhT, E, CH, NB);
  scanA_kernel<<<nb2,       b256, 0, stream>>>(bhT, bhpref, bsum2, NH);
  scanB_kernel<<<1,         64,   0, stream>>>(bsum2, nb2);
  binC_kernel <<<NBLK,      b256, 0, stream>>>(ei, ei+E, bhpref, bsum2, ebuf, E, CH, NB);
  binD_kernel <<<NB,        b256, 0, stream>>>(ebuf, bhpref, bsum2, rowptr, col, n, E);
  gemm_kernel <<<(n+63)/64, b256, 0, stream>>>(xt, W, att_s, att_d, h, a_src, a_dst, n);
  agg_kernel  <<<(n+15)/16, b256, 0, stream>>>(h, a_src, a_dst, rowptr, col, xt, bias, g2, b2, out, n);
}

// Round 4
// 175.665 us; speedup vs baseline: 1.3673x; 1.0898x over previous
//
#include <hip/hip_runtime.h>
#include <hip/hip_bf16.h>

typedef unsigned short u16;
typedef unsigned int u32;
typedef __attribute__((ext_vector_type(8))) short short8;   // 8 bf16 = 4 VGPRs
typedef __attribute__((ext_vector_type(4))) float f32x4;    // MFMA C/D frag

#define LRELU_SLOPE 0.2f
#define EPS_LN 1e-5f
#define EPS_SM 1e-16f
#define SCAN_CHUNK 4096   // 256 threads x 16 elems; chunk id = idx>>12
#define NBLK 256          // edge-chunk blocks for binA/binC
// Bucketed CSR build: bucket = dst>>7 (128 dsts/bucket). Requires n <= 65536
// (src packs in 16 bits) and NB <= 512 (LDS arrays). n = 50000 -> NB = 391.
// Pipeline (5 dispatches): ln1+binA -> scanA -> binC -> gemm+binD -> agg.

__device__ __forceinline__ float bflo(u32 u){ union{u32 i; float f;} x; x.i = u<<16; return x.f; }
__device__ __forceinline__ float bfhi(u32 u){ union{u32 i; float f;} x; x.i = u & 0xffff0000u; return x.f; }
__device__ __forceinline__ float bf1(u16 u){ union{u32 i; float f;} x; x.i = ((u32)u)<<16; return x.f; }
__device__ __forceinline__ u16 f2bf(float f){
  union{float f; u32 i;} x; x.f=f; u32 i=x.i;
  u32 r = (i + 0x7fffu + ((i>>16)&1u))>>16; return (u16)r;
}
__device__ __forceinline__ u32 pack2(float a, float b){ return (u32)f2bf(a) | ((u32)f2bf(b)<<16); }
__device__ __forceinline__ float lrelu(float x){ return x > 0.f ? x : LRELU_SLOPE*x; }

__device__ __forceinline__ float wsum(float v){
  #pragma unroll
  for(int o=32;o>0;o>>=1) v += __shfl_xor(v,o,64);
  return v;
}

// ---------------- K1: LN1 (xt = LayerNorm(x), bf16 out) + fused binA histogram ----
// Blocks < NBLK additionally build a per-chunk LDS histogram over NB coarse
// buckets (dst>>7) and store transposed counts bhT[b*NBLK + blk].
__global__ __launch_bounds__(256) void ln1A_kernel(const float* __restrict__ x,
    const float* __restrict__ g, const float* __restrict__ b,
    u16* __restrict__ xt, int n,
    const int* __restrict__ edst, int* __restrict__ bhT, int E, int CH, int NB){
  __shared__ u32 hist[512];
  int tid = threadIdx.x;
  bool doA = blockIdx.x < NBLK;
  if(doA){ for(int bb=tid; bb<NB; bb+=256) hist[bb]=0u; }

  int row  = blockIdx.x*4 + (tid>>6);
  int lane = tid & 63;
  if(row < n){
    float2 xv = ((const float2*)(x + (size_t)row*128))[lane];
    float v0 = xv.x, v1 = xv.y;
    float mean = wsum(v0+v1) * (1.f/128.f);
    float d0 = v0-mean, d1 = v1-mean;
    float var = wsum(d0*d0 + d1*d1) * (1.f/128.f);
    float rstd = rsqrtf(var + EPS_LN);
    float2 gv = ((const float2*)g)[lane], bv = ((const float2*)b)[lane];
    float o0 = d0*rstd*gv.x + bv.x;
    float o1 = d1*rstd*gv.y + bv.y;
    ((u32*)(xt + (size_t)row*128))[lane] = pack2(o0, o1);
  }
  if(doA){
    __syncthreads();
    int i = blockIdx.x;
    int e0=i*CH, e1=min(E, e0+CH);
    for(int e=e0+tid; e<e1; e+=256) atomicAdd(&hist[(u32)edst[e]>>7], 1u);
    __syncthreads();
    for(int bb=tid; bb<NB; bb+=256) bhT[bb*NBLK + i] = (int)hist[bb];
  }
}

// ---------------- K2: scanA — chunk-local exclusive prefixes + chunk sums ---------
__global__ __launch_bounds__(256) void scanA_kernel(const int* __restrict__ deg,
    int* __restrict__ pref, int* __restrict__ bsum, int n){
  __shared__ int part[256];
  int tid = threadIdx.x;
  int base = blockIdx.x*SCAN_CHUNK + tid*16;
  int v[16]; int s=0;
  #pragma unroll
  for(int i=0;i<16;i++){ int idx=base+i; int xv=(idx<n)? deg[idx]:0; v[i]=s; s+=xv; }
  part[tid]=s; __syncthreads();
  int mys=s;
  for(int off=1;off<256;off<<=1){
    int t = (tid>=off)? part[tid-off] : 0;
    __syncthreads(); part[tid]+=t; __syncthreads();
  }
  int run = part[tid]-mys;
  #pragma unroll
  for(int i=0;i<16;i++){
    int idx=base+i;
    if(idx<=n) pref[idx]=v[i]+run;
  }
  if(tid==255) bsum[blockIdx.x]=part[255];
}

// ---------------- K3: binC — bucket placement (inline chunk-sum scan) -------------
__global__ __launch_bounds__(256) void binC_kernel(const int* __restrict__ src,
    const int* __restrict__ dst, const int* __restrict__ bhpref, const int* __restrict__ bsum2,
    u32* __restrict__ ebuf, int E, int CH, int NB, int nb2){
  __shared__ u32 cur[512];
  __shared__ int boff[64];
  int tid = threadIdx.x, i = blockIdx.x;
  if(tid<64){
    int v = (tid<nb2)? bsum2[tid] : 0;
    int inc = v;
    #pragma unroll
    for(int o=1;o<64;o<<=1){ int t=__shfl_up(inc,o,64); if(tid>=o) inc+=t; }
    boff[tid] = inc - v;
  }
  __syncthreads();
  for(int bb=tid; bb<NB; bb+=256){
    int j = bb*NBLK + i;
    cur[bb] = (u32)(bhpref[j] + boff[j>>12]);
  }
  __syncthreads();
  int e0=i*CH, e1=min(E, e0+CH);
  for(int e=e0+tid; e<e1; e+=256){
    u32 s = (u32)src[e], d = (u32)dst[e];
    u32 pos = atomicAdd(&cur[d>>7], 1u);
    ebuf[pos] = s | ((d & 127u) << 16);
  }
}

// ---------------- K4: MFMA GEMM (h = xt@W + logits) + fused binD ------------------
// Blocks < NB first run binD: per-bucket LDS count/scan -> absolute rowptr +
// in-bucket scatter into col (u16). Then all blocks run the GEMM tile.
__global__ __launch_bounds__(256) void gemmD_kernel(const u16* __restrict__ xt,
    const float* __restrict__ W, const float* __restrict__ att_src, const float* __restrict__ att_dst,
    u16* __restrict__ h, float* __restrict__ a_src, float* __restrict__ a_dst, int n,
    const u32* __restrict__ ebuf, const int* __restrict__ bhpref, const int* __restrict__ bsum2,
    int* __restrict__ rowptr, u16* __restrict__ col, int NB, int nb2, int E){
  __shared__ u16 Wf[16384];      // 32 KB frag-major W
  __shared__ u16 Xb[64*136];     // 17 KB bf16 xt tile; reused for h staging
  __shared__ int dcnt[128], dcur[128], dboff[64];
  int tid = threadIdx.x;

  // ---- phase 1: binD (blocks < NB) ----
  if(blockIdx.x < (u32)NB){
    int bkt = blockIdx.x;
    if(tid<64){
      int v = (tid<nb2)? bsum2[tid] : 0;
      int inc = v;
      #pragma unroll
      for(int o=1;o<64;o<<=1){ int t=__shfl_up(inc,o,64); if(tid>=o) inc+=t; }
      dboff[tid] = inc - v;
    }
    if(tid<128) dcnt[tid]=0;
    __syncthreads();
    int j0 = bkt*NBLK, j1 = (bkt+1)*NBLK;
    int base = bhpref[j0] + dboff[j0>>12];
    int end  = bhpref[j1] + dboff[j1>>12];
    int cb = end - base;
    for(int k=tid; k<cb; k+=256) atomicAdd(&dcnt[(ebuf[base+k]>>16)&127], 1);
    __syncthreads();
    for(int o=1;o<128;o<<=1){           // inclusive scan (Hillis-Steele)
      int t = (tid>=o && tid<128)? dcnt[tid-o] : 0;
      __syncthreads();
      if(tid<128) dcnt[tid]+=t;
      __syncthreads();
    }
    int nd = min(128, n - (bkt<<7));
    if(tid<128){
      int excl = tid? dcnt[tid-1] : 0;
      dcur[tid] = excl;
      if(tid<nd) rowptr[(bkt<<7)+tid] = base + excl;
    }
    if(bkt==0 && tid==0) rowptr[n] = E;
    __syncthreads();
    for(int k=tid; k<cb; k+=256){
      u32 v = ebuf[base+k];
      int l = (int)((v>>16)&127u);
      int p = atomicAdd(&dcur[l], 1);
      col[base+p] = (u16)(v & 0xffffu);
    }
  }

  // ---- phase 2: GEMM tile ----
  int r0 = blockIdx.x*64;
  const float4* W4 = (const float4*)W;
  for(int p=tid; p<2048; p+=256){
    int g = p & 31, kk = p >> 5;
    int k0 = kk*2, n0 = g*4;
    float4 w0 = W4[k0*32 + g];
    float4 w1 = W4[(k0+1)*32 + g];
    int ks = k0>>5, q = (k0>>3)&3, j = k0&7;   // j even
    float e0[4] = {w0.x,w0.y,w0.z,w0.w};
    float e1[4] = {w1.x,w1.y,w1.z,w1.w};
    #pragma unroll
    for(int u=0;u<4;u++){
      int nn = n0+u;
      int idx = (((nn>>4)*4 + ks)*64 + q*16 + (nn&15))*8 + j;
      ((u32*)Wf)[idx>>1] = pack2(e0[u], e1[u]);
    }
  }
  for(int i=tid; i<1024; i+=256){
    int row = i>>4, seg = i&15;
    int gr = r0+row;
    uint4 v = (gr<n) ? ((const uint4*)(xt + (size_t)gr*128))[seg] : make_uint4(0,0,0,0);
    *(uint4*)&Xb[row*136 + seg*8] = v;
  }
  __syncthreads();

  int w = tid>>6, lane = tid&63;
  int slab = w*16, c = lane&15, q = lane>>4;
  f32x4 acc[8];
  #pragma unroll
  for(int t=0;t<8;t++) acc[t] = (f32x4){0.f,0.f,0.f,0.f};
  #pragma unroll
  for(int ks=0;ks<4;ks++){
    short8 A = *(const short8*)&Xb[(slab + c)*136 + ks*32 + q*8];
    #pragma unroll
    for(int t=0;t<8;t++){
      short8 B = *(const short8*)&Wf[((t*4+ks)*64 + lane)*8];
      acc[t] = __builtin_amdgcn_mfma_f32_16x16x32_bf16(A, B, acc[t], 0, 0, 0);
    }
  }
  __syncthreads();   // all waves done reading Xb
  #pragma unroll
  for(int t=0;t<8;t++){
    #pragma unroll
    for(int r=0;r<4;r++){
      Xb[(slab + q*4 + r)*136 + t*16 + c] = f2bf(acc[t][r]);   // C/D: col=lane&15, row=q*4+reg
    }
  }
  __syncthreads();
  {
    int row = tid>>2, qt = tid&3;
    int gr = r0+row;
    if(gr<n){
      const uint4* src = (const uint4*)((const char*)Xb + row*272 + qt*64);
      uint4* dst = (uint4*)((char*)(h + (size_t)gr*128) + qt*64);
      dst[0] = src[0];
      dst[1] = src[1];
      dst[2] = src[2];
      dst[3] = src[3];
    }
    int hd = qt;
    if(gr<n){
      float as=0.f, ad=0.f;
      const u16* hp = &Xb[row*136 + hd*32];
      #pragma unroll
      for(int sgm=0;sgm<4;sgm++){
        #pragma unroll
        for(int e=0;e<8;e++){
          float v = bf1(hp[sgm*8+e]);
          as = fmaf(v, att_src[hd*32+sgm*8+e], as);
          ad = fmaf(v, att_dst[hd*32+sgm*8+e], ad);
        }
      }
      a_src[(size_t)gr*4+hd] = as;
      a_dst[(size_t)gr*4+hd] = ad;
    }
  }
}

// ---------------- K5: Aggregation — softmax + gather + residual + LN2 -------------
// 16-lane group per dst, 4 dsts per wave. li owns channels li*8..li*8+7 (head
// hc=li>>2). Broadcast path: per 16-edge chunk the y-pass stages (y0..y3, sx) in
// wave-private LDS (group regions bank-skewed: stride 68/17 dwords -> the 4
// groups of a wave read distinct banks, each address a 4/16-lane broadcast).
// Inner loop = 2 ds_read_b32 per edge instead of 5 ds_bpermute + select chain.
// Per-group trip count (own deg) also skips padded gathers. No max-subtraction
// softmax (logits small; clamp 60).
__global__ __launch_bounds__(256) void agg_kernel(const u16* __restrict__ h,
    const float* __restrict__ a_src, const float* __restrict__ a_dst,
    const int* __restrict__ rowptr, const u16* __restrict__ col,
    const u16* __restrict__ xt, const float* __restrict__ bias,
    const float* __restrict__ g2, const float* __restrict__ b2,
    float* __restrict__ out, int n){
  __shared__ float ybuf[16*68];   // 16 groups x (16 slots x 4 dwords + 4 skew)
  __shared__ int   sxbuf[16*17];  // 16 groups x (16 slots + 1 skew)
  int lane = threadIdx.x & 63;
  int wv   = threadIdx.x >> 6;
  int g    = lane >> 4;        // group within wave
  int li   = lane & 15;        // lane within group
  int hc   = li >> 2;          // head of this lane's 8 channels
  int gid  = wv*4 + g;
  float* yb = ybuf  + gid*68;
  int*   sb = sxbuf + gid*17;
  int d    = blockIdx.x*16 + gid;
  bool dok = d < n;
  int dc   = dok ? d : (n-1);  // clamped: keep lanes alive for shfls

  float4 ad  = ((const float4*)a_dst)[dc];
  float4 asd = ((const float4*)a_src)[dc];
  float ad_h = hc==0? ad.x  : hc==1? ad.y  : hc==2? ad.z  : ad.w;
  float as_h = hc==0? asd.x : hc==1? asd.y : hc==2? asd.z : asd.w;
  float t_h  = __expf(fminf(lrelu(as_h + ad_h), 60.f));   // self-loop term, own head

  int base = rowptr[dc];
  int deg  = dok ? (rowptr[dc+1] - base) : 0;
  int dm = deg;                       // wave-uniform max degree
  dm = max(dm, __shfl_xor(dm, 16, 64));
  dm = max(dm, __shfl_xor(dm, 32, 64));

  float p0=0.f,p1=0.f,p2=0.f,p3=0.f;
  float acc[8]={};
  for(int j0=0;j0<dm;j0+=16){
    int j = j0 + li;
    bool vv = j < deg;
    int sx = vv ? (int)col[base+j] : 0;
    float4 a = ((const float4*)a_src)[sx];
    float y0 = vv ? __expf(fminf(lrelu(a.x+ad.x),60.f)) : 0.f;
    float y1 = vv ? __expf(fminf(lrelu(a.y+ad.y),60.f)) : 0.f;
    float y2 = vv ? __expf(fminf(lrelu(a.z+ad.z),60.f)) : 0.f;
    float y3 = vv ? __expf(fminf(lrelu(a.w+ad.w),60.f)) : 0.f;
    p0+=y0; p1+=y1; p2+=y2; p3+=y3;
    *(float4*)&yb[li*4] = make_float4(y0,y1,y2,y3);   // wave-private stage
    sb[li] = sx;
    __builtin_amdgcn_sched_barrier(0);
    int ccm = min(deg - j0, 16);      // own group's trip count
    for(int jj=0; jj<ccm; jj++){
      float al = yb[jj*4 + hc];
      int   sj = sb[jj];
      uint4 hv = *(const uint4*)(h + (size_t)sj*128 + li*8);
      acc[0]=fmaf(al,bflo(hv.x),acc[0]); acc[1]=fmaf(al,bfhi(hv.x),acc[1]);
      acc[2]=fmaf(al,bflo(hv.y),acc[2]); acc[3]=fmaf(al,bfhi(hv.y),acc[3]);
      acc[4]=fmaf(al,bflo(hv.z),acc[4]); acc[5]=fmaf(al,bfhi(hv.z),acc[5]);
      acc[6]=fmaf(al,bflo(hv.w),acc[6]); acc[7]=fmaf(al,bfhi(hv.w),acc[7]);
    }
    __builtin_amdgcn_sched_barrier(0);
  }
  // 16-lane group reduction of the per-head exp sums (serves 4 dsts per step)
  #pragma unroll
  for(int o=1;o<16;o<<=1){
    p0+=__shfl_xor(p0,o,64); p1+=__shfl_xor(p1,o,64);
    p2+=__shfl_xor(p2,o,64); p3+=__shfl_xor(p3,o,64);
  }
  float den = (hc==0? p0 : hc==1? p1 : hc==2? p2 : p3) + t_h + EPS_SM;
  // self-loop message (each lane owns its channels)
  uint4 hd4 = *(const uint4*)(h + (size_t)dc*128 + li*8);
  acc[0]=fmaf(t_h,bflo(hd4.x),acc[0]); acc[1]=fmaf(t_h,bfhi(hd4.x),acc[1]);
  acc[2]=fmaf(t_h,bflo(hd4.y),acc[2]); acc[3]=fmaf(t_h,bfhi(hd4.y),acc[3]);
  acc[4]=fmaf(t_h,bflo(hd4.z),acc[4]); acc[5]=fmaf(t_h,bfhi(hd4.z),acc[5]);
  acc[6]=fmaf(t_h,bflo(hd4.w),acc[6]); acc[7]=fmaf(t_h,bfhi(hd4.w),acc[7]);
  float inv = 1.f/den;

  // bias + residual (bf16 xt) + LN2 (each channel counted once over 16 lanes -> /128)
  uint4 xv4 = *(const uint4*)(xt + (size_t)dc*128 + li*8);
  const float* bp = bias + li*8;
  float4 ba = *(const float4*)bp, bb = *(const float4*)(bp+4);
  float r[8];
  r[0]=bflo(xv4.x)+acc[0]*inv+ba.x; r[1]=bfhi(xv4.x)+acc[1]*inv+ba.y;
  r[2]=bflo(xv4.y)+acc[2]*inv+ba.z; r[3]=bfhi(xv4.y)+acc[3]*inv+ba.w;
  r[4]=bflo(xv4.z)+acc[4]*inv+bb.x; r[5]=bfhi(xv4.z)+acc[5]*inv+bb.y;
  r[6]=bflo(xv4.w)+acc[6]*inv+bb.z; r[7]=bfhi(xv4.w)+acc[7]*inv+bb.w;
  float part=0;
  #pragma unroll
  for(int c=0;c<8;c++) part+=r[c];
  #pragma unroll
  for(int o=1;o<16;o<<=1) part += __shfl_xor(part,o,64);
  float mean = part*(1.f/128.f);
  float vp=0;
  #pragma unroll
  for(int c=0;c<8;c++){ float dd=r[c]-mean; vp+=dd*dd; }
  #pragma unroll
  for(int o=1;o<16;o<<=1) vp += __shfl_xor(vp,o,64);
  float var = vp*(1.f/128.f);
  float rstd = rsqrtf(var+EPS_LN);
  const float* gp = g2 + li*8; const float* b2p = b2 + li*8;
  float4 ga = *(const float4*)gp,  gb = *(const float4*)(gp+4);
  float4 c2a= *(const float4*)b2p, c2b= *(const float4*)(b2p+4);
  if(dok){
    float* op = out + (size_t)d*128 + li*8;
    float4 o0 = make_float4((r[0]-mean)*rstd*ga.x+c2a.x, (r[1]-mean)*rstd*ga.y+c2a.y,
                            (r[2]-mean)*rstd*ga.z+c2a.z, (r[3]-mean)*rstd*ga.w+c2a.w);
    float4 o1 = make_float4((r[4]-mean)*rstd*gb.x+c2b.x, (r[5]-mean)*rstd*gb.y+c2b.y,
                            (r[6]-mean)*rstd*gb.z+c2b.z, (r[7]-mean)*rstd*gb.w+c2b.w);
    *(float4*)op     = o0;
    *(float4*)(op+4) = o1;
  }
}

extern "C" void kernel_launch(void* const* d_in, const int* in_sizes, int n_in,
                              void* d_out, int out_size, void* d_ws, size_t ws_size,
                              hipStream_t stream) {
  const float* x     = (const float*)d_in[0];
  const int*   ei    = (const int*)d_in[1];
  const float* W     = (const float*)d_in[4];
  const float* att_s = (const float*)d_in[5];
  const float* att_d = (const float*)d_in[6];
  const float* bias  = (const float*)d_in[7];
  const float* g1    = (const float*)d_in[8];
  const float* b1    = (const float*)d_in[9];
  const float* g2    = (const float*)d_in[10];
  const float* b2    = (const float*)d_in[11];
  int n = in_sizes[0]/128;
  int E = in_sizes[1]/2;
  float* out = (float*)d_out;

  int NB  = (n+127)>>7;                // coarse buckets (391 for n=50000)
  int CH  = (E + NBLK - 1)/NBLK;       // edges per binA/binC block
  int NH  = NB*NBLK;                   // flattened (bucket,block) table size
  int nb2 = NH/SCAN_CHUNK + 1;         // scan chunks over the table (25)

  char* ws = (char*)d_ws;              // ws_size = 256 MiB; ~36 MB used, no overlays
  u16*   xt     = (u16*)ws;   ws += (size_t)n*128*2;
  u16*   h      = (u16*)ws;   ws += (size_t)n*128*2;
  float* a_src  = (float*)ws; ws += (size_t)n*4*4;
  float* a_dst  = (float*)ws; ws += (size_t)n*4*4;
  int*   rowptr = (int*)ws;   ws += (((size_t)(n+1)*4 + 255) & ~(size_t)255);
  u16*   col    = (u16*)ws;   ws += (((size_t)E*2 + 255) & ~(size_t)255);
  u32*   ebuf   = (u32*)ws;   ws += (size_t)E*4;
  int*   bhT    = (int*)ws;   ws += (size_t)NH*4;
  int*   bhpref = (int*)ws;   ws += (((size_t)(NH+1)*4 + 255) & ~(size_t)255);
  int*   bsum2  = (int*)ws;   ws += 256*4;

  dim3 b256(256);
  ln1A_kernel <<<(n+3)/4,   b256, 0, stream>>>(x, g1, b1, xt, n, ei+E, bhT, E, CH, NB);
  scanA_kernel<<<nb2,       b256, 0, stream>>>(bhT, bhpref, bsum2, NH);
  binC_kernel <<<NBLK,      b256, 0, stream>>>(ei, ei+E, bhpref, bsum2, ebuf, E, CH, NB, nb2);
  gemmD_kernel<<<(n+63)/64, b256, 0, stream>>>(xt, W, att_s, att_d, h, a_src, a_dst, n,
                                               ebuf, bhpref, bsum2, rowptr, col, NB, nb2, E);
  agg_kernel  <<<(n+15)/16, b256, 0, stream>>>(h, a_src, a_dst, rowptr, col, xt, bias, g2, b2, out, n);
}